// Round 17
// baseline (220.505 us; speedup 1.0000x reference)
//
#include <hip/hip_runtime.h>

typedef unsigned short u16;
typedef unsigned int u32;
typedef __attribute__((ext_vector_type(8))) short s16x8;
typedef __attribute__((ext_vector_type(4))) float f32x4;

#define NN 50000
#define NE 600000
#define NG 64

__device__ __forceinline__ u16 f2bf(float f) {
    u32 u = __float_as_uint(f);
    u32 r = (u + 0x7fffu + ((u >> 16) & 1u)) >> 16;
    return (u16)r;
}
__device__ __forceinline__ float bf2f(u16 h) {
    return __uint_as_float(((u32)h) << 16);
}

// ---------------- CSR build ----------------
__global__ void k_hist(const int* __restrict__ dst, int* __restrict__ cnt, int ne) {
    int e = blockIdx.x * blockDim.x + threadIdx.x;
    if (e < ne) atomicAdd(&cnt[dst[e]], 1);
}

__global__ __launch_bounds__(256)
void k_scan1(const int* __restrict__ cnt, int* __restrict__ bsum, int n) {
    int i = blockIdx.x * 256 + threadIdx.x;
    int v = (i < n) ? cnt[i] : 0;
#pragma unroll
    for (int off = 32; off > 0; off >>= 1) v += __shfl_down(v, off, 64);
    __shared__ int ws[4];
    int lane = threadIdx.x & 63, w = threadIdx.x >> 6;
    if (lane == 0) ws[w] = v;
    __syncthreads();
    if (threadIdx.x == 0) bsum[blockIdx.x] = ws[0] + ws[1] + ws[2] + ws[3];
}

__global__ __launch_bounds__(256)
void k_scan2(int* __restrict__ bsum, int nb) {
    int t = threadIdx.x;
    int v = (t < nb) ? bsum[t] : 0;
    int lane = t & 63, w = t >> 6;
    int inc = v;
#pragma unroll
    for (int off = 1; off < 64; off <<= 1) {
        int x = __shfl_up(inc, off, 64);
        if (lane >= off) inc += x;
    }
    __shared__ int wtot[4];
    if (lane == 63) wtot[w] = inc;
    __syncthreads();
    int wo = 0;
    for (int j = 0; j < w; ++j) wo += wtot[j];
    if (t < nb) bsum[t] = wo + inc - v;   // exclusive
}

__global__ __launch_bounds__(256)
void k_scan3(const int* __restrict__ cnt, const int* __restrict__ boff,
             int* __restrict__ rowptr, int* __restrict__ cursor,
             float* __restrict__ dinv, int n) {
    int i = blockIdx.x * 256 + threadIdx.x;
    int v = (i < n) ? cnt[i] : 0;
    int lane = threadIdx.x & 63, w = threadIdx.x >> 6;
    int inc = v;
#pragma unroll
    for (int off = 1; off < 64; off <<= 1) {
        int x = __shfl_up(inc, off, 64);
        if (lane >= off) inc += x;
    }
    __shared__ int wtot[4];
    if (lane == 63) wtot[w] = inc;
    __syncthreads();
    int wo = boff[blockIdx.x];
    for (int j = 0; j < w; ++j) wo += wtot[j];
    if (i < n) {
        int excl = wo + inc - v;
        rowptr[i] = excl;
        cursor[i] = excl;
        dinv[i] = rsqrtf(1.0f + (float)v);
        if (i == n - 1) rowptr[n] = excl + v;
    }
}

// fill stores (src, dinv[src]) pairs
__global__ void k_fill(const int* __restrict__ src, const int* __restrict__ dst,
                       const float* __restrict__ dinv,
                       int* __restrict__ cursor, uint2* __restrict__ csr2, int ne) {
    int e = blockIdx.x * blockDim.x + threadIdx.x;
    if (e < ne) {
        int pos = atomicAdd(&cursor[dst[e]], 1);
        int s = src[e];
        csr2[pos] = make_uint2((u32)s, __float_as_uint(dinv[s]));
    }
}

// ---------------- fused preamble ----------------
__device__ __forceinline__ void wsplit_tiled(const float* __restrict__ W,
                                             u16* __restrict__ hi, int gid) {
    int n = gid & 255, kgrp = gid >> 8;
    int kbase = kgrp * 8;
#pragma unroll
    for (int j = 0; j < 8; ++j) {
        float w = W[(size_t)(kbase + j) * 256 + n];
        hi[(size_t)gid * 8 + j] = f2bf(w);
    }
}

// block ranges: [0,XB) xbf | [16) W1 | [32) W2 | [64) sums | [CB) cnt | [1] counts
__global__ __launch_bounds__(256)
void k_preamble(const float* __restrict__ x, u16* __restrict__ xbf,
                const float* __restrict__ W1, u16* __restrict__ w1hi,
                const float* __restrict__ W2, u16* __restrict__ w2hi,
                float* __restrict__ sums, int* __restrict__ cnt,
                const int* __restrict__ batch, float* __restrict__ counts) {
    const int XB = (NN * 32 + 255) / 256;        // x as float4: N*128/4 elems
    const int CB = (NN + 255) / 256;
    int b = blockIdx.x, t = threadIdx.x;
    if (b < XB) {
        int i = b * 256 + t;
        if (i < NN * 32) {
            float4 v = ((const float4*)x)[i];
            ushort4 o;
            o.x = f2bf(v.x); o.y = f2bf(v.y); o.z = f2bf(v.z); o.w = f2bf(v.w);
            ((ushort4*)xbf)[i] = o;
        }
        return;
    }
    b -= XB;
    if (b < 16) { wsplit_tiled(W1, w1hi, b * 256 + t); return; }   // 4096 groups
    b -= 16;
    if (b < 32) { wsplit_tiled(W2, w2hi, b * 256 + t); return; }   // 8192 groups
    b -= 32;
    if (b < 64) { sums[b * 256 + t] = 0.f; return; }
    b -= 64;
    if (b < CB) {
        int i = b * 256 + t;
        if (i < NN) cnt[i] = 0;
        return;
    }
    b -= CB;
    if (b == 0) {   // counts via binary search on sorted batch
        __shared__ int lb[65];
        if (t <= 64) {
            int lo = 0, hi = NN;
            while (lo < hi) {
                int mid = (lo + hi) >> 1;
                if (batch[mid] < t) lo = mid + 1; else hi = mid;
            }
            lb[t] = lo;
        }
        __syncthreads();
        if (t < 64) counts[t] = (float)(lb[t + 1] - lb[t]);
    }
}

// ---------------- fma helpers ----------------
__device__ __forceinline__ void fma8(float* a, const uint4& v, float w) {
    a[0] += bf2f((u16)v.x) * w; a[1] += bf2f((u16)(v.x >> 16)) * w;
    a[2] += bf2f((u16)v.y) * w; a[3] += bf2f((u16)(v.y >> 16)) * w;
    a[4] += bf2f((u16)v.z) * w; a[5] += bf2f((u16)(v.z >> 16)) * w;
    a[6] += bf2f((u16)v.w) * w; a[7] += bf2f((u16)(v.w >> 16)) * w;
}
__device__ __forceinline__ void fma4(float* a, const uint2& v, float w) {
    a[0] += bf2f((u16)v.x) * w; a[1] += bf2f((u16)(v.x >> 16)) * w;
    a[2] += bf2f((u16)v.y) * w; a[3] += bf2f((u16)(v.y >> 16)) * w;
}

// ---------------- FUSED gather + MFMA GEMM ----------------
// Block = 512 thr / 8 waves, owns 128 output rows.
// Phase 1: each wave gathers 16 nodes (2 at a time: 32 lanes/node) from row-major
//   bf16 source hb, accumulates fp32, writes bf16 A-panel into LDS [128][K] with
//   XOR slot swizzle (slot' = slot ^ ((r ^ r>>2)&3), 16B slots).
// Phase 2: one barrier, then barrier-free K-loop: A frags from LDS, B pre-tiled
//   [kgrp][n][8] from L2, MFMA accumulate. Epilogue: bias+relu -> bf16 out, or
//   run-length pooled atomics (POOL).
template<bool POOL, int K>
__global__ __launch_bounds__(512, 4)
void k_fused(const int* __restrict__ rowptr, const uint2* __restrict__ csr2,
             const float* __restrict__ dinv, const u16* __restrict__ hb,
             const u16* __restrict__ Bh, const float* __restrict__ bias,
             u16* __restrict__ out_bf, const int* __restrict__ batch,
             float* __restrict__ pool, int M) {
    __shared__ u16 ldsA[128 * K];
    const int tid = threadIdx.x, lane = tid & 63, wid = tid >> 6;
    const int bm = blockIdx.x * 128;
    constexpr int VL = K / 32;           // bf16 per lane in gather (8 or 4)

    // ---- phase 1: gather ----
    {
        int sl = lane & 31;
        int half = lane >> 5;
        for (int it = 0; it < 8; ++it) {
            int row = wid * 16 + it * 2 + half;
            int node = bm + row; if (node >= M) node = M - 1;
            int beg = rowptr[node];
            int m = rowptr[node + 1] - beg;
            float di = dinv[node];
            float a0[VL], a1[VL];
            if constexpr (VL == 8) {
                uint4 v = ((const uint4*)hb)[(size_t)node * 32 + sl];
#pragma unroll
                for (int i = 0; i < 8; ++i) a1[i] = 0.f;
                a0[0] = bf2f((u16)v.x) * di; a0[1] = bf2f((u16)(v.x >> 16)) * di;
                a0[2] = bf2f((u16)v.y) * di; a0[3] = bf2f((u16)(v.y >> 16)) * di;
                a0[4] = bf2f((u16)v.z) * di; a0[5] = bf2f((u16)(v.z >> 16)) * di;
                a0[6] = bf2f((u16)v.w) * di; a0[7] = bf2f((u16)(v.w >> 16)) * di;
            } else {
                uint2 v = ((const uint2*)hb)[(size_t)node * 32 + sl];
#pragma unroll
                for (int i = 0; i < 4; ++i) a1[i] = 0.f;
                a0[0] = bf2f((u16)v.x) * di; a0[1] = bf2f((u16)(v.x >> 16)) * di;
                a0[2] = bf2f((u16)v.y) * di; a0[3] = bf2f((u16)(v.y >> 16)) * di;
            }
            const uint2* ep = csr2 + beg;
            int e = 0;
            for (; e + 4 <= m; e += 4) {
                uint2 e0 = ep[e], e1 = ep[e + 1], e2 = ep[e + 2], e3 = ep[e + 3];
                float w0 = __uint_as_float(e0.y), w1 = __uint_as_float(e1.y);
                float w2 = __uint_as_float(e2.y), w3 = __uint_as_float(e3.y);
                if constexpr (VL == 8) {
                    uint4 r0 = ((const uint4*)hb)[(size_t)e0.x * 32 + sl];
                    uint4 r1 = ((const uint4*)hb)[(size_t)e1.x * 32 + sl];
                    uint4 r2 = ((const uint4*)hb)[(size_t)e2.x * 32 + sl];
                    uint4 r3 = ((const uint4*)hb)[(size_t)e3.x * 32 + sl];
                    fma8(a0, r0, w0); fma8(a1, r1, w1); fma8(a0, r2, w2); fma8(a1, r3, w3);
                } else {
                    uint2 r0 = ((const uint2*)hb)[(size_t)e0.x * 32 + sl];
                    uint2 r1 = ((const uint2*)hb)[(size_t)e1.x * 32 + sl];
                    uint2 r2 = ((const uint2*)hb)[(size_t)e2.x * 32 + sl];
                    uint2 r3 = ((const uint2*)hb)[(size_t)e3.x * 32 + sl];
                    fma4(a0, r0, w0); fma4(a1, r1, w1); fma4(a0, r2, w2); fma4(a1, r3, w3);
                }
            }
            for (; e < m; ++e) {
                uint2 e0 = ep[e];
                float w0 = __uint_as_float(e0.y);
                if constexpr (VL == 8) {
                    uint4 r0 = ((const uint4*)hb)[(size_t)e0.x * 32 + sl];
                    fma8(a0, r0, w0);
                } else {
                    uint2 r0 = ((const uint2*)hb)[(size_t)e0.x * 32 + sl];
                    fma4(a0, r0, w0);
                }
            }
            int swzr = (row ^ (row >> 2)) & 3;
            if constexpr (VL == 8) {
                uint4 o;
                o.x = (u32)f2bf((a0[0] + a1[0]) * di) | ((u32)f2bf((a0[1] + a1[1]) * di) << 16);
                o.y = (u32)f2bf((a0[2] + a1[2]) * di) | ((u32)f2bf((a0[3] + a1[3]) * di) << 16);
                o.z = (u32)f2bf((a0[4] + a1[4]) * di) | ((u32)f2bf((a0[5] + a1[5]) * di) << 16);
                o.w = (u32)f2bf((a0[6] + a1[6]) * di) | ((u32)f2bf((a0[7] + a1[7]) * di) << 16);
                *(uint4*)&ldsA[row * K + ((sl ^ swzr) << 3)] = o;
            } else {
                uint2 o;
                o.x = (u32)f2bf((a0[0] + a1[0]) * di) | ((u32)f2bf((a0[1] + a1[1]) * di) << 16);
                o.y = (u32)f2bf((a0[2] + a1[2]) * di) | ((u32)f2bf((a0[3] + a1[3]) * di) << 16);
                int slot = sl >> 1, hf = sl & 1;
                *(uint2*)&ldsA[row * K + (((slot ^ swzr) << 3) + hf * 4)] = o;
            }
        }
    }
    __syncthreads();

    // ---- phase 2: GEMM (no barriers, no staging) ----
    const int wr = (wid >> 2) * 64, wc = (wid & 3) * 64;
    const int lr = lane & 15, kg = lane >> 4;
    const u16* bh_p = Bh + (u32)kg * 2048 + (u32)(wc + lr) * 8;

    f32x4 acc[4][4];
#pragma unroll
    for (int i = 0; i < 4; ++i)
#pragma unroll
        for (int j = 0; j < 4; ++j) acc[i][j] = (f32x4){0.f, 0.f, 0.f, 0.f};

    constexpr int nt = K >> 5;
#pragma unroll
    for (int t = 0; t < nt; ++t) {
        s16x8 bh[4];
#pragma unroll
        for (int fn = 0; fn < 4; ++fn)
            bh[fn] = *(const s16x8*)&bh_p[(u32)t * 8192 + (u32)fn * 128];
        s16x8 a[4];
#pragma unroll
        for (int fm = 0; fm < 4; ++fm) {
            int r = wr + fm * 16 + lr;
            a[fm] = *(const s16x8*)&ldsA[r * K + (((t * 4 + kg) ^ ((r ^ (r >> 2)) & 3)) << 3)];
        }
#pragma unroll
        for (int fn = 0; fn < 4; ++fn)
#pragma unroll
            for (int fm = 0; fm < 4; ++fm)
                acc[fm][fn] = __builtin_amdgcn_mfma_f32_16x16x32_bf16(a[fm], bh[fn], acc[fm][fn], 0, 0, 0);
    }

    // epilogue: row = bm + wr + fm*16 + kg*4 + r ; col = wc + fn*16 + lr
#pragma unroll
    for (int fn = 0; fn < 4; ++fn) {
        int col = wc + fn * 16 + lr;
        float bv = bias[col];
        if (!POOL) {
#pragma unroll
            for (int fm = 0; fm < 4; ++fm) {
                int rbase = bm + wr + fm * 16 + kg * 4;
#pragma unroll
                for (int r = 0; r < 4; ++r) {
                    int row = rbase + r;
                    if (row < M)
                        out_bf[(size_t)row * 256 + col] = f2bf(fmaxf(acc[fm][fn][r] + bv, 0.f));
                }
            }
        } else {
            int gcur = -1;
            float run = 0.f;
#pragma unroll
            for (int fm = 0; fm < 4; ++fm) {
                int rbase = bm + wr + fm * 16 + kg * 4;
#pragma unroll
                for (int r = 0; r < 4; ++r) {
                    int row = rbase + r;
                    if (row < M) {
                        int g = batch[row];
                        float v = fmaxf(acc[fm][fn][r] + bv, 0.f);
                        if (g != gcur) {
                            if (gcur >= 0) atomicAdd(&pool[gcur * 256 + col], run);
                            gcur = g;
                            run = 0.f;
                        }
                        run += v;
                    }
                }
            }
            if (gcur >= 0) atomicAdd(&pool[gcur * 256 + col], run);
        }
    }
}

// ---------------- dense head ----------------
__global__ __launch_bounds__(128)
void k_dense(const float* __restrict__ sums, const float* __restrict__ counts,
             const float* __restrict__ W3, const float* __restrict__ b3,
             const float* __restrict__ W4, const float* __restrict__ b4,
             float* __restrict__ out) {
    __shared__ float g[256];
    __shared__ float hid[128];
    int gi = blockIdx.x;
    int t = threadIdx.x;
    float inv = 1.0f / fmaxf(counts[gi], 1.0f);
    for (int c = t; c < 256; c += 128) g[c] = sums[gi * 256 + c] * inv;
    __syncthreads();
    float acc = b3[t];
    for (int k = 0; k < 256; ++k) acc += g[k] * W3[k * 128 + t];
    hid[t] = fmaxf(acc, 0.0f);
    __syncthreads();
    if (t < 10) {
        float o = b4[t];
        for (int k = 0; k < 128; ++k) o += hid[k] * W4[k * 10 + t];
        out[gi * 10 + t] = o;
    }
}

extern "C" void kernel_launch(void* const* d_in, const int* in_sizes, int n_in,
                              void* d_out, int out_size, void* d_ws, size_t ws_size,
                              hipStream_t stream) {
    const float* x   = (const float*)d_in[0];
    const int*  eidx = (const int*)d_in[1];    // [2, NE]
    const int*  batch= (const int*)d_in[2];
    const float* W1 = (const float*)d_in[3];
    const float* b1 = (const float*)d_in[4];
    const float* W2 = (const float*)d_in[5];
    const float* b2 = (const float*)d_in[6];
    const float* W3 = (const float*)d_in[7];
    const float* b3 = (const float*)d_in[8];
    const float* W4 = (const float*)d_in[9];
    const float* b4 = (const float*)d_in[10];
    float* out = (float*)d_out;

    const int N = NN, E = NE, G = NG;
    const int* src = eidx;
    const int* dst = eidx + E;
    const int NB = (N + 255) / 256;

    // workspace layout (256B-aligned slices)
    char* p = (char*)d_ws;
    auto alloc = [&](size_t bytes) { char* r = p; p += (bytes + 255) & ~(size_t)255; return r; };
    u16*   h1bf   = (u16*)alloc((size_t)N * 256 * 2);   // bf16 h1 row-major
    u16*   xbf    = (u16*)alloc((size_t)N * 128 * 2);   // bf16 x row-major
    float* dinv   = (float*)alloc((size_t)N * 4);
    float* sums   = (float*)alloc((size_t)G * 256 * 4);
    float* counts = (float*)alloc((size_t)G * 4);
    int*   cnt    = (int*)alloc((size_t)N * 4);         // reused as cursor after scan
    int*   rowptr = (int*)alloc((size_t)(N + 1) * 4);
    int*   bsum   = (int*)alloc((size_t)NB * 4);
    uint2* csr2   = (uint2*)alloc((size_t)E * 8);       // (src, dinv[src])
    u16*   w1hi   = (u16*)alloc((size_t)256 * 128 * 2); // pre-tiled [kgrp][n][8]
    u16*   w2hi   = (u16*)alloc((size_t)256 * 256 * 2);
    int*   cursor = cnt;

    // fused preamble: xbf, tiled wsplits (single bf16), zero sums, zero cnt, counts
    const int XB = (NN * 32 + 255) / 256;
    const int CB = (NN + 255) / 256;
    int pre_blocks = XB + 16 + 32 + 64 + CB + 1;
    k_preamble<<<pre_blocks, 256, 0, stream>>>(x, xbf, W1, w1hi, W2, w2hi,
                                               sums, cnt, batch, counts);

    // CSR build + dinv
    k_hist<<<(E + 255) / 256, 256, 0, stream>>>(dst, cnt, E);
    k_scan1<<<NB, 256, 0, stream>>>(cnt, bsum, N);
    k_scan2<<<1, 256, 0, stream>>>(bsum, NB);
    k_scan3<<<NB, 256, 0, stream>>>(cnt, bsum, rowptr, cursor, dinv, N);
    k_fill<<<(E + 255) / 256, 256, 0, stream>>>(src, dst, dinv, cursor, csr2, E);

    int gblocks = (N + 127) / 128;
    // conv1: fused gather(x,128ch) + GEMM K=128 -> h1bf (bias+relu, bf16)
    k_fused<false, 128><<<gblocks, 512, 0, stream>>>(rowptr, csr2, dinv, xbf, w1hi, b1,
                                                     h1bf, nullptr, nullptr, N);
    // conv2: fused gather(h1,256ch) + GEMM K=256 -> pooled sums
    k_fused<true, 256><<<gblocks, 512, 0, stream>>>(rowptr, csr2, dinv, h1bf, w2hi, b2,
                                                    nullptr, batch, sums, N);

    // dense head
    k_dense<<<G, 128, 0, stream>>>(sums, counts, W3, b3, W4, b4, out);
}

// Round 18
// 218.124 us; speedup vs baseline: 1.0109x; 1.0109x over previous
//
#include <hip/hip_runtime.h>

typedef unsigned short u16;
typedef unsigned int u32;
typedef __attribute__((ext_vector_type(8))) short s16x8;
typedef __attribute__((ext_vector_type(4))) float f32x4;

#define NN 50000
#define NE 600000
#define NG 64

__device__ __forceinline__ u16 f2bf(float f) {
    u32 u = __float_as_uint(f);
    u32 r = (u + 0x7fffu + ((u >> 16) & 1u)) >> 16;
    return (u16)r;
}
__device__ __forceinline__ float bf2f(u16 h) {
    return __uint_as_float(((u32)h) << 16);
}
__device__ __forceinline__ void gll16(const void* g, void* l) {
    __builtin_amdgcn_global_load_lds((const __attribute__((address_space(1))) u32*)g,
                                     (__attribute__((address_space(3))) u32*)l, 16, 0, 0);
}

// ---------------- scans ----------------
__global__ __launch_bounds__(256)
void k_scan1(const int* __restrict__ cnt, int* __restrict__ bsum, int n) {
    int i = blockIdx.x * 256 + threadIdx.x;
    int v = (i < n) ? cnt[i] : 0;
#pragma unroll
    for (int off = 32; off > 0; off >>= 1) v += __shfl_down(v, off, 64);
    __shared__ int ws[4];
    int lane = threadIdx.x & 63, w = threadIdx.x >> 6;
    if (lane == 0) ws[w] = v;
    __syncthreads();
    if (threadIdx.x == 0) bsum[blockIdx.x] = ws[0] + ws[1] + ws[2] + ws[3];
}

__global__ __launch_bounds__(256)
void k_scan2(int* __restrict__ bsum, int nb) {
    int t = threadIdx.x;
    int v = (t < nb) ? bsum[t] : 0;
    int lane = t & 63, w = t >> 6;
    int inc = v;
#pragma unroll
    for (int off = 1; off < 64; off <<= 1) {
        int x = __shfl_up(inc, off, 64);
        if (lane >= off) inc += x;
    }
    __shared__ int wtot[4];
    if (lane == 63) wtot[w] = inc;
    __syncthreads();
    int wo = 0;
    for (int j = 0; j < w; ++j) wo += wtot[j];
    if (t < nb) bsum[t] = wo + inc - v;   // exclusive
}

__global__ __launch_bounds__(256)
void k_scan3(const int* __restrict__ cnt, const int* __restrict__ boff,
             int* __restrict__ rowptr, int* __restrict__ cursor,
             float* __restrict__ dinv, int n) {
    int i = blockIdx.x * 256 + threadIdx.x;
    int v = (i < n) ? cnt[i] : 0;
    int lane = threadIdx.x & 63, w = threadIdx.x >> 6;
    int inc = v;
#pragma unroll
    for (int off = 1; off < 64; off <<= 1) {
        int x = __shfl_up(inc, off, 64);
        if (lane >= off) inc += x;
    }
    __shared__ int wtot[4];
    if (lane == 63) wtot[w] = inc;
    __syncthreads();
    int wo = boff[blockIdx.x];
    for (int j = 0; j < w; ++j) wo += wtot[j];
    if (i < n) {
        int excl = wo + inc - v;
        rowptr[i] = excl;
        cursor[i] = excl;
        dinv[i] = rsqrtf(1.0f + (float)v);
        if (i == n - 1) rowptr[n] = excl + v;
    }
}

// fill stores (src, dinv[src]) pairs
__global__ void k_fill(const int* __restrict__ src, const int* __restrict__ dst,
                       const float* __restrict__ dinv,
                       int* __restrict__ cursor, uint2* __restrict__ csr2, int ne) {
    int e = blockIdx.x * blockDim.x + threadIdx.x;
    if (e < ne) {
        int pos = atomicAdd(&cursor[dst[e]], 1);
        int s = src[e];
        csr2[pos] = make_uint2((u32)s, __float_as_uint(dinv[s]));
    }
}

// ---------------- fused preamble (now includes hist; cnt pre-zeroed by memset) ----------------
__device__ __forceinline__ void wsplit_tiled(const float* __restrict__ W,
                                             u16* __restrict__ hi, int gid) {
    int n = gid & 255, kgrp = gid >> 8;
    int kbase = kgrp * 8;
#pragma unroll
    for (int j = 0; j < 8; ++j) {
        float w = W[(size_t)(kbase + j) * 256 + n];
        hi[(size_t)gid * 8 + j] = f2bf(w);
    }
}

// block ranges: [0,XB) xbf | [16) W1 | [32) W2 | [1] counts | [HB) hist
__global__ __launch_bounds__(256)
void k_preamble(const float* __restrict__ x, u16* __restrict__ xbf,
                const float* __restrict__ W1, u16* __restrict__ w1hi,
                const float* __restrict__ W2, u16* __restrict__ w2hi,
                const int* __restrict__ batch, float* __restrict__ counts,
                const int* __restrict__ dst, int* __restrict__ cnt) {
    const int XB = (NN * 32 + 255) / 256;        // x as float4: N*128/4 elems
    int b = blockIdx.x, t = threadIdx.x;
    if (b < XB) {
        int i = b * 256 + t;
        if (i < NN * 32) {
            float4 v = ((const float4*)x)[i];
            ushort4 o;
            o.x = f2bf(v.x); o.y = f2bf(v.y); o.z = f2bf(v.z); o.w = f2bf(v.w);
            ((ushort4*)xbf)[i] = o;
        }
        return;
    }
    b -= XB;
    if (b < 16) { wsplit_tiled(W1, w1hi, b * 256 + t); return; }   // 4096 groups
    b -= 16;
    if (b < 32) { wsplit_tiled(W2, w2hi, b * 256 + t); return; }   // 8192 groups
    b -= 32;
    if (b == 0) {   // counts via binary search on sorted batch
        __shared__ int lb[65];
        if (t <= 64) {
            int lo = 0, hi = NN;
            while (lo < hi) {
                int mid = (lo + hi) >> 1;
                if (batch[mid] < t) lo = mid + 1; else hi = mid;
            }
            lb[t] = lo;
        }
        __syncthreads();
        if (t < 64) counts[t] = (float)(lb[t + 1] - lb[t]);
        return;
    }
    b -= 1;
    {   // hist: cnt pre-zeroed by hipMemsetAsync before this kernel
        int e = b * 256 + t;
        if (e < NE) atomicAdd(&cnt[dst[e]], 1);
    }
}

// ---------------- gather aggregation: 2 nodes/wave, 32 lanes/node ----------------
__device__ __forceinline__ void fma8(float* a, const uint4& v, float w) {
    a[0] += bf2f((u16)v.x) * w; a[1] += bf2f((u16)(v.x >> 16)) * w;
    a[2] += bf2f((u16)v.y) * w; a[3] += bf2f((u16)(v.y >> 16)) * w;
    a[4] += bf2f((u16)v.z) * w; a[5] += bf2f((u16)(v.z >> 16)) * w;
    a[6] += bf2f((u16)v.w) * w; a[7] += bf2f((u16)(v.w >> 16)) * w;
}
__device__ __forceinline__ void fma4(float* a, const uint2& v, float w) {
    a[0] += bf2f((u16)v.x) * w; a[1] += bf2f((u16)(v.x >> 16)) * w;
    a[2] += bf2f((u16)v.y) * w; a[3] += bf2f((u16)(v.y >> 16)) * w;
}

template<int C>   // C=256: uint4/lane (8 bf16); C=128: uint2/lane (4 bf16)
__global__ __launch_bounds__(256)
void k_agg_gather(const int* __restrict__ rowptr, const uint2* __restrict__ csr2,
                  const float* __restrict__ dinv, const u16* __restrict__ hb,
                  u16* __restrict__ out, int n) {
    constexpr int VL = C / 32;           // bf16 per lane (8 or 4)
    int tid = threadIdx.x;
    int node = (blockIdx.x * 256 + tid) >> 5;
    if (node >= n) return;
    int sl = tid & 31;                   // lane within node's 32-lane group
    int beg = rowptr[node];
    int m = rowptr[node + 1] - beg;
    float di = dinv[node];
    float a0[VL], a1[VL];
    if constexpr (VL == 8) {
        uint4 v = ((const uint4*)hb)[(size_t)node * 32 + sl];
#pragma unroll
        for (int i = 0; i < 8; ++i) a1[i] = 0.f;
        a0[0] = bf2f((u16)v.x) * di; a0[1] = bf2f((u16)(v.x >> 16)) * di;
        a0[2] = bf2f((u16)v.y) * di; a0[3] = bf2f((u16)(v.y >> 16)) * di;
        a0[4] = bf2f((u16)v.z) * di; a0[5] = bf2f((u16)(v.z >> 16)) * di;
        a0[6] = bf2f((u16)v.w) * di; a0[7] = bf2f((u16)(v.w >> 16)) * di;
    } else {
        uint2 v = ((const uint2*)hb)[(size_t)node * 32 + sl];
#pragma unroll
        for (int i = 0; i < 4; ++i) a1[i] = 0.f;
        a0[0] = bf2f((u16)v.x) * di; a0[1] = bf2f((u16)(v.x >> 16)) * di;
        a0[2] = bf2f((u16)v.y) * di; a0[3] = bf2f((u16)(v.y >> 16)) * di;
    }
    const uint2* ep = csr2 + beg;
    int e = 0;
    for (; e + 4 <= m; e += 4) {
        uint2 e0 = ep[e], e1 = ep[e + 1], e2 = ep[e + 2], e3 = ep[e + 3];
        float w0 = __uint_as_float(e0.y), w1 = __uint_as_float(e1.y);
        float w2 = __uint_as_float(e2.y), w3 = __uint_as_float(e3.y);
        if constexpr (VL == 8) {
            uint4 r0 = ((const uint4*)hb)[(size_t)e0.x * 32 + sl];
            uint4 r1 = ((const uint4*)hb)[(size_t)e1.x * 32 + sl];
            uint4 r2 = ((const uint4*)hb)[(size_t)e2.x * 32 + sl];
            uint4 r3 = ((const uint4*)hb)[(size_t)e3.x * 32 + sl];
            fma8(a0, r0, w0); fma8(a1, r1, w1); fma8(a0, r2, w2); fma8(a1, r3, w3);
        } else {
            uint2 r0 = ((const uint2*)hb)[(size_t)e0.x * 32 + sl];
            uint2 r1 = ((const uint2*)hb)[(size_t)e1.x * 32 + sl];
            uint2 r2 = ((const uint2*)hb)[(size_t)e2.x * 32 + sl];
            uint2 r3 = ((const uint2*)hb)[(size_t)e3.x * 32 + sl];
            fma4(a0, r0, w0); fma4(a1, r1, w1); fma4(a0, r2, w2); fma4(a1, r3, w3);
        }
    }
    for (; e < m; ++e) {
        uint2 e0 = ep[e];
        float w0 = __uint_as_float(e0.y);
        if constexpr (VL == 8) {
            uint4 r0 = ((const uint4*)hb)[(size_t)e0.x * 32 + sl];
            fma8(a0, r0, w0);
        } else {
            uint2 r0 = ((const uint2*)hb)[(size_t)e0.x * 32 + sl];
            fma4(a0, r0, w0);
        }
    }
    if constexpr (VL == 8) {
        uint4 o;
        o.x = (u32)f2bf((a0[0] + a1[0]) * di) | ((u32)f2bf((a0[1] + a1[1]) * di) << 16);
        o.y = (u32)f2bf((a0[2] + a1[2]) * di) | ((u32)f2bf((a0[3] + a1[3]) * di) << 16);
        o.z = (u32)f2bf((a0[4] + a1[4]) * di) | ((u32)f2bf((a0[5] + a1[5]) * di) << 16);
        o.w = (u32)f2bf((a0[6] + a1[6]) * di) | ((u32)f2bf((a0[7] + a1[7]) * di) << 16);
        ((uint4*)out)[(size_t)node * 32 + sl] = o;
    } else {
        uint2 o;
        o.x = (u32)f2bf((a0[0] + a1[0]) * di) | ((u32)f2bf((a0[1] + a1[1]) * di) << 16);
        o.y = (u32)f2bf((a0[2] + a1[2]) * di) | ((u32)f2bf((a0[3] + a1[3]) * di) << 16);
        ((uint2*)out)[(size_t)node * 32 + sl] = o;
    }
}

// ---------------- MFMA GEMM (R9 structure, single-bf16 B) ----------------
template<bool POOL>
__global__ __launch_bounds__(512, 4)
void k_gemm_mfma(const u16* __restrict__ A, const u16* __restrict__ Bh,
                 const float* __restrict__ bias, u16* __restrict__ out_bf,
                 const int* __restrict__ batch, float* __restrict__ pool,
                 int M, int K) {
    __shared__ u16 ldsA[2][4096];   // 2 x 8KB: [128 rows][4 slots of 8 bf16]
    const int tid = threadIdx.x, lane = tid & 63, wid = tid >> 6;
    const int bm = blockIdx.x * 128;
    const int wr = (wid >> 2) * 64, wc = (wid & 3) * 64;
    const int lr = lane & 15, kg = lane >> 4;

    const int srow = wid * 16 + (lane >> 2);            // local row 0..127
    const int sslot = lane & 3;
    const int ssw = (srow ^ (srow >> 2)) & 3;
    int srg = bm + srow; if (srg >= M) srg = M - 1;
    const u16* sbase = A + (size_t)srg * K + ((sslot ^ ssw) << 3);

    const u16* bh_p = Bh + (u32)kg * 2048 + (u32)(wc + lr) * 8;

    f32x4 acc[4][4];
#pragma unroll
    for (int i = 0; i < 4; ++i)
#pragma unroll
        for (int j = 0; j < 4; ++j) acc[i][j] = (f32x4){0.f, 0.f, 0.f, 0.f};

    const int nt = K >> 5;
    gll16(sbase, &ldsA[0][wid * 512]);
    __syncthreads();

    for (int t = 0; t < nt; ++t) {
        int cur = t & 1;
        if (t + 1 < nt)
            gll16(sbase + ((t + 1) << 5), &ldsA[cur ^ 1][wid * 512]);

        s16x8 bh[4];
#pragma unroll
        for (int fn = 0; fn < 4; ++fn)
            bh[fn] = *(const s16x8*)&bh_p[(u32)t * 8192 + (u32)fn * 128];
        const u16* lb = ldsA[cur];
        s16x8 a[4];
#pragma unroll
        for (int fm = 0; fm < 4; ++fm) {
            int r = wr + fm * 16 + lr;
            a[fm] = *(const s16x8*)&lb[r * 32 + ((kg ^ ((r ^ (r >> 2)) & 3)) << 3)];
        }
#pragma unroll
        for (int fn = 0; fn < 4; ++fn)
#pragma unroll
            for (int fm = 0; fm < 4; ++fm)
                acc[fm][fn] = __builtin_amdgcn_mfma_f32_16x16x32_bf16(a[fm], bh[fn], acc[fm][fn], 0, 0, 0);
        __syncthreads();
    }

    // epilogue: row = bm + wr + fm*16 + kg*4 + r ; col = wc + fn*16 + lr
#pragma unroll
    for (int fn = 0; fn < 4; ++fn) {
        int col = wc + fn * 16 + lr;
        float bv = bias[col];
        if (!POOL) {
#pragma unroll
            for (int fm = 0; fm < 4; ++fm) {
                int rbase = bm + wr + fm * 16 + kg * 4;
#pragma unroll
                for (int r = 0; r < 4; ++r) {
                    int row = rbase + r;
                    if (row < M)
                        out_bf[(size_t)row * 256 + col] = f2bf(fmaxf(acc[fm][fn][r] + bv, 0.f));
                }
            }
        } else {
            int gcur = -1;
            float run = 0.f;
#pragma unroll
            for (int fm = 0; fm < 4; ++fm) {
                int rbase = bm + wr + fm * 16 + kg * 4;
#pragma unroll
                for (int r = 0; r < 4; ++r) {
                    int row = rbase + r;
                    if (row < M) {
                        int g = batch[row];
                        float v = fmaxf(acc[fm][fn][r] + bv, 0.f);
                        if (g != gcur) {
                            if (gcur >= 0) atomicAdd(&pool[gcur * 256 + col], run);
                            gcur = g;
                            run = 0.f;
                        }
                        run += v;
                    }
                }
            }
            if (gcur >= 0) atomicAdd(&pool[gcur * 256 + col], run);
        }
    }
}

// ---------------- dense head ----------------
__global__ __launch_bounds__(128)
void k_dense(const float* __restrict__ sums, const float* __restrict__ counts,
             const float* __restrict__ W3, const float* __restrict__ b3,
             const float* __restrict__ W4, const float* __restrict__ b4,
             float* __restrict__ out) {
    __shared__ float g[256];
    __shared__ float hid[128];
    int gi = blockIdx.x;
    int t = threadIdx.x;
    float inv = 1.0f / fmaxf(counts[gi], 1.0f);
    for (int c = t; c < 256; c += 128) g[c] = sums[gi * 256 + c] * inv;
    __syncthreads();
    float acc = b3[t];
    for (int k = 0; k < 256; ++k) acc += g[k] * W3[k * 128 + t];
    hid[t] = fmaxf(acc, 0.0f);
    __syncthreads();
    if (t < 10) {
        float o = b4[t];
        for (int k = 0; k < 128; ++k) o += hid[k] * W4[k * 10 + t];
        out[gi * 10 + t] = o;
    }
}

extern "C" void kernel_launch(void* const* d_in, const int* in_sizes, int n_in,
                              void* d_out, int out_size, void* d_ws, size_t ws_size,
                              hipStream_t stream) {
    const float* x   = (const float*)d_in[0];
    const int*  eidx = (const int*)d_in[1];    // [2, NE]
    const int*  batch= (const int*)d_in[2];
    const float* W1 = (const float*)d_in[3];
    const float* b1 = (const float*)d_in[4];
    const float* W2 = (const float*)d_in[5];
    const float* b2 = (const float*)d_in[6];
    const float* W3 = (const float*)d_in[7];
    const float* b3 = (const float*)d_in[8];
    const float* W4 = (const float*)d_in[9];
    const float* b4 = (const float*)d_in[10];
    float* out = (float*)d_out;

    const int N = NN, E = NE, G = NG;
    const int* src = eidx;
    const int* dst = eidx + E;
    const int NB = (N + 255) / 256;

    // workspace layout (256B-aligned slices)
    char* p = (char*)d_ws;
    auto alloc = [&](size_t bytes) { char* r = p; p += (bytes + 255) & ~(size_t)255; return r; };
    u16*   h1bf   = (u16*)alloc((size_t)N * 256 * 2);   // bf16 h1 row-major
    u16*   xbf    = (u16*)alloc((size_t)N * 128 * 2);   // bf16 x row-major
    float* dinv   = (float*)alloc((size_t)N * 4);
    float* sums   = (float*)alloc((size_t)G * 256 * 4);
    float* counts = (float*)alloc((size_t)G * 4);
    int*   cnt    = (int*)alloc((size_t)N * 4);         // reused as cursor after scan
    int*   rowptr = (int*)alloc((size_t)(N + 1) * 4);
    int*   bsum   = (int*)alloc((size_t)NB * 4);
    uint2* csr2   = (uint2*)alloc((size_t)E * 8);       // (src, dinv[src])
    u16*   agg1   = (u16*)alloc((size_t)N * 128 * 2);   // row-major aggregated x
    u16*   agg2   = (u16*)alloc((size_t)N * 256 * 2);   // row-major aggregated h1
    u16*   w1hi   = (u16*)alloc((size_t)256 * 128 * 2); // pre-tiled [kgrp][n][8]
    u16*   w2hi   = (u16*)alloc((size_t)256 * 256 * 2);
    int*   cursor = cnt;

    // zero cnt + sums up front (graph-capture-safe async memsets)
    hipMemsetAsync(cnt, 0, (size_t)N * 4, stream);
    hipMemsetAsync(sums, 0, (size_t)G * 256 * 4, stream);

    // fused preamble: xbf, tiled wsplits, counts, hist (cnt pre-zeroed)
    const int XB = (NN * 32 + 255) / 256;
    const int HB = (NE + 255) / 256;
    int pre_blocks = XB + 16 + 32 + 1 + HB;
    k_preamble<<<pre_blocks, 256, 0, stream>>>(x, xbf, W1, w1hi, W2, w2hi,
                                               batch, counts, dst, cnt);

    // scans + fill
    k_scan1<<<NB, 256, 0, stream>>>(cnt, bsum, N);
    k_scan2<<<1, 256, 0, stream>>>(bsum, NB);
    k_scan3<<<NB, 256, 0, stream>>>(cnt, bsum, rowptr, cursor, dinv, N);
    k_fill<<<(E + 255) / 256, 256, 0, stream>>>(src, dst, dinv, cursor, csr2, E);

    // conv1: gather-aggregate xbf (128ch) -> bf16 A, GEMM K=128 -> h1bf
    k_agg_gather<128><<<(N + 7) / 8, 256, 0, stream>>>(rowptr, csr2, dinv, xbf, agg1, N);
    int gblocks = (N + 127) / 128;
    k_gemm_mfma<false><<<gblocks, 512, 0, stream>>>(agg1, w1hi, b1, h1bf,
                                                    nullptr, nullptr, N, 128);

    // conv2: gather-aggregate h1bf (256ch) -> bf16 A, GEMM K=256 + pool
    k_agg_gather<256><<<(N + 7) / 8, 256, 0, stream>>>(rowptr, csr2, dinv, h1bf, agg2, N);
    k_gemm_mfma<true><<<gblocks, 512, 0, stream>>>(agg2, w2hi, b2, nullptr,
                                                   batch, sums, N, 256);

    // dense head
    k_dense<<<G, 128, 0, stream>>>(sums, counts, W3, b3, W4, b4, out);
}